// Round 3
// baseline (496.797 us; speedup 1.0000x reference)
//
#include <hip/hip_runtime.h>

#define DEVINL static __device__ __forceinline__

typedef __attribute__((ext_vector_type(4)))  float f32x4;
typedef __attribute__((ext_vector_type(16))) float f32x16;
typedef __attribute__((ext_vector_type(4)))  float float4_t;
typedef __attribute__((ext_vector_type(8)))  short short8;
typedef __attribute__((ext_vector_type(4)))  short short4v;
typedef __attribute__((ext_vector_type(4)))  int   int4v;

DEVINL unsigned short f2bf(float f){
  union { float f; unsigned int u; } x; x.f = f;
  return (unsigned short)((x.u + 0x7fffu + ((x.u >> 16) & 1u)) >> 16);
}
DEVINL float bf2f(unsigned short h){
  union { unsigned int u; float f; } x; x.u = ((unsigned int)h) << 16;
  return x.f;
}
DEVINL f32x4 zero4(){ f32x4 z; z[0]=0.f; z[1]=0.f; z[2]=0.f; z[3]=0.f; return z; }
DEVINL f32x16 zero16(){ f32x16 z;
#pragma unroll
  for (int e=0;e<16;++e) z[e]=0.f;
  return z; }

// async global->LDS, 16B per lane, LDS dest = wave-uniform base + lane*16 (linear)
#define GLL16(gp, lp) __builtin_amdgcn_global_load_lds( \
    (const __attribute__((address_space(1))) void*)(gp), \
    (__attribute__((address_space(3))) void*)(lp), 16, 0, 0)

// ---------------- prep: f32 -> bf16 casts ----------------
__global__ __launch_bounds__(256) void cast_f32_bf16(const float* __restrict__ src,
                                                     unsigned short* __restrict__ dst, int n8){
  int i = blockIdx.x * 256 + threadIdx.x;
  if (i >= n8) return;
  const float4_t* s = (const float4_t*)src;
  float4_t a = s[2*i], b = s[2*i+1];
  short8 o;
  o[0]=(short)f2bf(a[0]); o[1]=(short)f2bf(a[1]); o[2]=(short)f2bf(a[2]); o[3]=(short)f2bf(a[3]);
  o[4]=(short)f2bf(b[0]); o[5]=(short)f2bf(b[1]); o[6]=(short)f2bf(b[2]); o[7]=(short)f2bf(b[3]);
  *(short8*)(dst + (size_t)i*8) = o;
}

// EmT[g][h] = softmax(ent,axis=-1)[h][g] * (log2(e)/sqrt(D)); rows g=16..31 zero-padded.
__global__ __launch_bounds__(256) void prep_em(const float* __restrict__ ent,
                                               unsigned short* __restrict__ EmT){
  int t = threadIdx.x;
  if (t < 16){
    float v[16]; float mx = -3.0e38f;
#pragma unroll
    for (int j=0;j<16;++j){ v[j] = ent[t*16 + j]; mx = fmaxf(mx, v[j]); }
    float s = 0.f;
#pragma unroll
    for (int j=0;j<16;++j){ v[j] = __expf(v[j]-mx); s += v[j]; }
    float inv = (1.f/s) * 0.125f * 1.4426950408889634f;
#pragma unroll
    for (int j=0;j<16;++j) EmT[j*16 + t] = f2bf(v[j]*inv);
  }
  EmT[256 + t] = 0; // zero pad rows 16..31 (256 entries)
}

// ---------------- mask [B][1][S][S] int32 -> bit-packed [B][S][S/32] ----------------
__global__ __launch_bounds__(256) void prep_maskbits(const int* __restrict__ mask,
                                                     unsigned* __restrict__ mb){
  int id = blockIdx.x * 256 + threadIdx.x;   // 8*1024*32 = 262144 words
  const int* src = mask + (size_t)id * 32;
  unsigned word = 0u;
#pragma unroll
  for (int c=0;c<8;++c){
    int4v v = *(const int4v*)(src + c*4);
    word |= (unsigned)(v[0]!=0) << (c*4)
          | (unsigned)(v[1]!=0) << (c*4+1)
          | (unsigned)(v[2]!=0) << (c*4+2)
          | (unsigned)(v[3]!=0) << (c*4+3);
  }
  mb[id] = word;
}

// ---------------- GEMM: C = A(bf16,[M][1024]) * W^T(bf16,[N][K] row-major) + bias ----------------
// MODE 0: out bf16 in [B][H][S][D] head layout (+ z*8388608 elem offset for Q/K/V)
// MODE 1: out f32 row-major [M][N]
template<int MODE>
__global__ __launch_bounds__(256) void gemm_bt(const unsigned short* __restrict__ A,
                                               const unsigned short* __restrict__ W4,
                                               const float* __restrict__ bias0,
                                               const float* __restrict__ bias1,
                                               const float* __restrict__ bias2,
                                               void* __restrict__ outp){
  __shared__ __align__(16) unsigned short As[4096]; // [128][32] bf16
  __shared__ __align__(16) unsigned short Bs[4096];
  const int tid = threadIdx.x;
  const int w = tid >> 6, ln = tid & 63;
  const int wm = w >> 1, wn = w & 1;
  const int lq = ln & 15, lg = ln >> 4;
  const int m0 = blockIdx.y * 128, n0 = blockIdx.x * 128;
  const int z = blockIdx.z;
  const unsigned short* Bt = W4 + (size_t)z * 1048576;
  const float* bias = (z == 0) ? bias0 : ((z == 1) ? bias1 : bias2);

  const unsigned short* Ag = A  + (size_t)(m0 + (tid >> 2)) * 1024 + (tid & 3) * 8;
  const unsigned short* Bg = Bt + (size_t)(n0 + (tid >> 2)) * 1024 + (tid & 3) * 8;
  unsigned short* lA0 = As + w * 512;
  unsigned short* lA1 = As + 2048 + w * 512;
  unsigned short* lB0 = Bs + w * 512;
  unsigned short* lB1 = Bs + 2048 + w * 512;

  f32x4 acc[4][4];
#pragma unroll
  for (int i=0;i<4;++i)
#pragma unroll
    for (int j=0;j<4;++j) acc[i][j] = zero4();

  for (int kb = 0; kb < 32; ++kb){
    const int k0 = kb * 32;
    GLL16(Ag + k0,         lA0);
    GLL16(Ag + k0 + 65536, lA1);
    GLL16(Bg + k0,         lB0);
    GLL16(Bg + k0 + 65536, lB1);
    __syncthreads();
    short8 af[4], bf_[4];
#pragma unroll
    for (int i=0;i<4;++i) af[i]  = *(const short8*)(As + (wm*64 + i*16 + lq)*32 + lg*8);
#pragma unroll
    for (int j=0;j<4;++j) bf_[j] = *(const short8*)(Bs + (wn*64 + j*16 + lq)*32 + lg*8);
#pragma unroll
    for (int i=0;i<4;++i)
#pragma unroll
      for (int j=0;j<4;++j)
        acc[i][j] = __builtin_amdgcn_mfma_f32_16x16x32_bf16(af[i], bf_[j], acc[i][j], 0, 0, 0);
    __syncthreads();
  }

  const int mrow = m0 + wm*64, ncol = n0 + wn*64;
  float bj[4];
#pragma unroll
  for (int j=0;j<4;++j) bj[j] = bias[ncol + j*16 + lq];
#pragma unroll
  for (int i=0;i<4;++i)
#pragma unroll
    for (int j=0;j<4;++j)
#pragma unroll
      for (int r=0;r<4;++r){
        float v = acc[i][j][r] + bj[j];
        int m = mrow + i*16 + lg*4 + r;
        int n = ncol + j*16 + lq;
        if (MODE == 0){
          int bb = m >> 10, sI = m & 1023, h = n >> 6, d = n & 63;
          ((unsigned short*)outp)[(size_t)z*8388608 + (((size_t)bb*16 + h)*1024 + sI)*64 + d] = f2bf(v);
        } else {
          ((float*)outp)[(size_t)m*1024 + n] = v;
        }
      }
}

// ---------------- V [bh][s][d] -> Vt [bh][d][s] ----------------
__global__ __launch_bounds__(256) void transpose_v(const unsigned short* __restrict__ V,
                                                   unsigned short* __restrict__ Vt){
  int idx = blockIdx.x * 256 + threadIdx.x;      // 128*64*128 = 1048576 total
  int s8 = idx & 127, d = (idx >> 7) & 63, bh = idx >> 13;
  const unsigned short* src = V + (size_t)bh*65536 + (size_t)s8*8*64 + d;
  short8 o;
#pragma unroll
  for (int j=0;j<8;++j) o[j] = (short)src[(size_t)j*64];
  *(short8*)(Vt + (size_t)bh*65536 + (size_t)d*1024 + (size_t)s8*8) = o;
}

// ---------------- fused attention with cross-head mix ----------------
// grid 512 blocks 1D (bid&7 = batch -> XCD-local K/V), 512 threads (8 waves), QBLK=16.
// wave w: QK^T heads 4*(w&3)..+3 on k-half (w>>2); mix q-rows {2w,2w+1};
// softmax+PV output heads {2w,2w+1} over the 16-row q-tile.
__global__ __launch_bounds__(512,4) void attn_fused(const unsigned short* __restrict__ Q,
    const unsigned short* __restrict__ K, const unsigned short* __restrict__ Vt,
    const unsigned* __restrict__ MB, const unsigned short* __restrict__ EmT,
    unsigned short* __restrict__ AO){
  __shared__ __align__(16) unsigned short sraw[8192]; // [q16][k32][h16] bf16, XOR-swizzled
  __shared__ __align__(16) unsigned short smix[8192]; // [g16][q16][k32] bf16, XOR-swizzled
  const int tid = threadIdx.x;
  const int w = tid >> 6, ln = tid & 63;
  const int lq = ln & 15, lg = ln >> 4;
  const int l5 = ln & 31, h5 = ln >> 5;
  const int bid = blockIdx.x;
  const int bb = bid & 7, q0 = (bid >> 3) * 16;
  const int aQ = w & 3, n0 = w >> 2, g0 = w * 2;

  const unsigned short* Qb = Q  + ((size_t)bb*16 + 4*aQ) * 65536;
  const unsigned short* Kb = K  + ((size_t)bb*16 + 4*aQ) * 65536 + (size_t)(n0*16 + lq)*64 + lg*8;
  const unsigned short* Vb = Vt + ((size_t)bb*16 + g0) * 65536;
  const unsigned* Mw = MB + (size_t)bb*32768 + (size_t)(q0 + lq)*32;

  // Em A-frag for 32x32x16: lane: EmT[l5][h5*8 + j]
  short8 emA = *(const short8*)(EmT + l5*16 + h5*8);

  // Q frags (persistent): rows q0 + lq, d = ks*32 + lg*8 + j
  short8 qf[4][2];
#pragma unroll
  for (int hh=0; hh<4; ++hh)
#pragma unroll
    for (int ks=0; ks<2; ++ks)
      qf[hh][ks] = *(const short8*)(Qb + (size_t)hh*65536 + (size_t)(q0 + lq)*64 + ks*32 + lg*8);

  f32x4 acco[2][4];
#pragma unroll
  for (int a=0;a<2;++a)
#pragma unroll
    for (int n=0;n<4;++n) acco[a][n] = zero4();
  float mst[2] = {-3.0e38f,-3.0e38f};
  float lst[2] = {0.f,0.f};

  const int kk = n0*16 + lq;

  for (int kt = 0; kt < 32; ++kt){
    const int kb = kt*32;
    // ---- QK^T: 4 heads x (16q x 16k half) ----
    f32x4 accs[4];
#pragma unroll
    for (int hh=0; hh<4; ++hh){
      short8 k0 = *(const short8*)(Kb + (size_t)hh*65536 + (size_t)kb*64);
      short8 k1 = *(const short8*)(Kb + (size_t)hh*65536 + (size_t)kb*64 + 32);
      accs[hh] = __builtin_amdgcn_mfma_f32_16x16x32_bf16(qf[hh][0], k0, zero4(), 0,0,0);
      accs[hh] = __builtin_amdgcn_mfma_f32_16x16x32_bf16(qf[hh][1], k1, accs[hh], 0,0,0);
    }
    // ---- write raw scores: sraw[q][k][h], pack 4 heads per 8B write ----
#pragma unroll
    for (int r=0;r<4;++r){
      const int qq = lg*4 + r;
      short4v pk;
      pk[0]=(short)f2bf(accs[0][r]); pk[1]=(short)f2bf(accs[1][r]);
      pk[2]=(short)f2bf(accs[2][r]); pk[3]=(short)f2bf(accs[3][r]);
      const int lin = (qq*32 + kk)*32 + aQ*8;
      const int sw  = (((kk>>2)&1)<<4) | (((qq>>2)&3)<<5);
      *(short4v*)((char*)sraw + (lin ^ sw)) = pk;
    }
    __syncthreads();
    // ---- head-mix: one 32x32x16 MFMA per q-row (M=g[16 used], N=k32, K=h16) ----
#pragma unroll
    for (int t=0;t<2;++t){
      const int qq = w*2 + t;
      const int lin = (qq*32 + l5)*32 + h5*16;
      const int sw  = (((l5>>2)&1)<<4) | (((qq>>2)&3)<<5);
      short8 sfr = *(const short8*)((const char*)sraw + (lin ^ sw));
      f32x16 md = __builtin_amdgcn_mfma_f32_32x32x16_bf16(emA, sfr, zero16(), 0,0,0);
#pragma unroll
      for (int reg=0;reg<8;++reg){
        const int gg = (reg&3) + 8*(reg>>2) + 4*h5;   // 32x32 C-layout rows < 16 kept
        int ob = gg*1024 + qq*64 + l5*2;
        ob ^= ((gg>>2)&1)<<6;
        *(short*)((char*)smix + ob) = (short)f2bf(md[reg]);
      }
    }
    __syncthreads();
    // ---- online softmax + PV (2 output heads per wave) ----
    const unsigned mw = Mw[kt];
    const unsigned mshift = mw >> (lg*8);
    const int allon = __all((int)((mshift & 0xffu) == 0xffu));
#pragma unroll
    for (int hh=0; hh<2; ++hh){
      const int gg = g0 + hh;
      const int rb = (gg*1024 + lq*64 + lg*16) ^ (((gg>>2)&1)<<6);
      short8 sm8 = *(const short8*)((const char*)smix + rb);
      short8 vfr[4];
#pragma unroll
      for (int n=0;n<4;++n)
        vfr[n] = *(const short8*)(Vb + (size_t)hh*65536 + (size_t)(n*16 + lq)*1024 + kb + lg*8);
      float s[8];
#pragma unroll
      for (int j=0;j<8;++j) s[j] = bf2f((unsigned short)sm8[j]);
      if (!allon){
#pragma unroll
        for (int j=0;j<8;++j) if (!((mshift>>j)&1u)) s[j] = -1.44269504e9f; // -1e9 * log2e
      }
      float pm = s[0];
#pragma unroll
      for (int j=1;j<8;++j) pm = fmaxf(pm, s[j]);
      pm = fmaxf(pm, __shfl_xor(pm, 16, 64));
      pm = fmaxf(pm, __shfl_xor(pm, 32, 64));
      const float mo = mst[hh];
      const float mn = fmaxf(mo, pm);
      const float sc = exp2f(mo - mn);
      float p[8]; float ps = 0.f;
#pragma unroll
      for (int j=0;j<8;++j){ p[j] = exp2f(s[j] - mn); ps += p[j]; }
      ps += __shfl_xor(ps, 16, 64);
      ps += __shfl_xor(ps, 32, 64);
      lst[hh] = lst[hh]*sc + ps;
      mst[hh] = mn;
      short8 pa;
#pragma unroll
      for (int j=0;j<8;++j) pa[j] = (short)f2bf(p[j]);
      const float scr0 = __shfl(sc, lg*4 + 0, 64);
      const float scr1 = __shfl(sc, lg*4 + 1, 64);
      const float scr2 = __shfl(sc, lg*4 + 2, 64);
      const float scr3 = __shfl(sc, lg*4 + 3, 64);
#pragma unroll
      for (int n=0;n<4;++n){
        acco[hh][n][0] *= scr0; acco[hh][n][1] *= scr1;
        acco[hh][n][2] *= scr2; acco[hh][n][3] *= scr3;
      }
#pragma unroll
      for (int n=0;n<4;++n)
        acco[hh][n] = __builtin_amdgcn_mfma_f32_16x16x32_bf16(pa, vfr[n], acco[hh][n], 0,0,0);
    }
  }
  // ---- normalize + write AO [B*S][E] bf16 ----
#pragma unroll
  for (int hh=0; hh<2; ++hh){
    const int gg = g0 + hh;
    const float linv = 1.0f / lst[hh];
    const float l0 = __shfl(linv, lg*4+0, 64), l1 = __shfl(linv, lg*4+1, 64);
    const float l2 = __shfl(linv, lg*4+2, 64), l3 = __shfl(linv, lg*4+3, 64);
#pragma unroll
    for (int n=0;n<4;++n){
      const int e = gg*64 + n*16 + lq;
      const size_t base = ((size_t)bb*1024 + (size_t)(q0 + lg*4))*1024 + e;
      AO[base         ] = f2bf(acco[hh][n][0]*l0);
      AO[base + 1024  ] = f2bf(acco[hh][n][1]*l1);
      AO[base + 2048  ] = f2bf(acco[hh][n][2]*l2);
      AO[base + 3072  ] = f2bf(acco[hh][n][3]*l3);
    }
  }
}

// ---------------- host launcher ----------------
extern "C" void kernel_launch(void* const* d_in, const int* in_sizes, int n_in,
                              void* d_out, int out_size, void* d_ws, size_t ws_size,
                              hipStream_t stream){
  const float* x   = (const float*)d_in[0];
  const int*   msk = (const int*)  d_in[1];
  const float* Wq  = (const float*)d_in[2];
  const float* bq  = (const float*)d_in[3];
  const float* Wk  = (const float*)d_in[4];
  const float* bk  = (const float*)d_in[5];
  const float* Wv  = (const float*)d_in[6];
  const float* bv  = (const float*)d_in[7];
  const float* Wo  = (const float*)d_in[8];
  const float* bo  = (const float*)d_in[9];
  const float* ent = (const float*)d_in[10];

  char* ws = (char*)d_ws;
  unsigned short* xb  = (unsigned short*)(ws);                 // 16 MiB  (later reused as Vt)
  unsigned short* Wb  = (unsigned short*)(ws + 16777216);      // 4 x 2 MiB bf16 weights
  unsigned short* qkv = (unsigned short*)(ws + 25165824);      // Q,K,V: 3 x 16 MiB
  unsigned short* EmT = (unsigned short*)(ws + 75497472);      // 1 KiB
  unsigned*       MB  = (unsigned*)     (ws + 75499520);       // 1 MiB bit-packed mask
  unsigned short* Vt  = xb;                                    // reuse (xb dead after GEMMs)
  unsigned short* AO  = qkv + (size_t)2*8388608;               // reuse V slot (dead after transpose)

  cast_f32_bf16<<<4096, 256, 0, stream>>>(x,  xb,            1048576);
  cast_f32_bf16<<<512,  256, 0, stream>>>(Wq, Wb,            131072);
  cast_f32_bf16<<<512,  256, 0, stream>>>(Wk, Wb + 1048576,  131072);
  cast_f32_bf16<<<512,  256, 0, stream>>>(Wv, Wb + 2097152,  131072);
  cast_f32_bf16<<<512,  256, 0, stream>>>(Wo, Wb + 3145728,  131072);
  prep_em<<<1, 256, 0, stream>>>(ent, EmT);
  prep_maskbits<<<1024, 256, 0, stream>>>(msk, MB);

  gemm_bt<0><<<dim3(8,64,3), 256, 0, stream>>>(xb, Wb, bq, bk, bv, (void*)qkv);
  transpose_v<<<4096, 256, 0, stream>>>(qkv + (size_t)2*8388608, Vt);
  attn_fused<<<512, 512, 0, stream>>>(qkv, qkv + 8388608, Vt, MB, EmT, AO);
  gemm_bt<1><<<dim3(8,64,1), 256, 0, stream>>>(AO, Wb + 3145728, bo, bo, bo, d_out);

  (void)in_sizes; (void)n_in; (void)out_size; (void)ws_size;
}

// Round 4
// 445.163 us; speedup vs baseline: 1.1160x; 1.1160x over previous
//
#include <hip/hip_runtime.h>

#define DEVINL static __device__ __forceinline__

typedef __attribute__((ext_vector_type(4)))  float f32x4;
typedef __attribute__((ext_vector_type(16))) float f32x16;
typedef __attribute__((ext_vector_type(4)))  float float4_t;
typedef __attribute__((ext_vector_type(8)))  short short8;
typedef __attribute__((ext_vector_type(4)))  short short4v;
typedef __attribute__((ext_vector_type(4)))  int   int4v;

DEVINL unsigned short f2bf(float f){
  union { float f; unsigned int u; } x; x.f = f;
  return (unsigned short)((x.u + 0x7fffu + ((x.u >> 16) & 1u)) >> 16);
}
DEVINL float bf2f(unsigned short h){
  union { unsigned int u; float f; } x; x.u = ((unsigned int)h) << 16;
  return x.f;
}
DEVINL f32x4 zero4(){ f32x4 z; z[0]=0.f; z[1]=0.f; z[2]=0.f; z[3]=0.f; return z; }
DEVINL f32x16 zero16(){ f32x16 z;
#pragma unroll
  for (int e=0;e<16;++e) z[e]=0.f;
  return z; }

// async global->LDS, 16B per lane, LDS dest = wave-uniform base + lane*16 (linear)
#define GLL16(gp, lp) __builtin_amdgcn_global_load_lds( \
    (const __attribute__((address_space(1))) void*)(gp), \
    (__attribute__((address_space(3))) void*)(lp), 16, 0, 0)

// ---------------- prep: f32 -> bf16 casts ----------------
__global__ __launch_bounds__(256) void cast_f32_bf16(const float* __restrict__ src,
                                                     unsigned short* __restrict__ dst, int n8){
  int i = blockIdx.x * 256 + threadIdx.x;
  if (i >= n8) return;
  const float4_t* s = (const float4_t*)src;
  float4_t a = s[2*i], b = s[2*i+1];
  short8 o;
  o[0]=(short)f2bf(a[0]); o[1]=(short)f2bf(a[1]); o[2]=(short)f2bf(a[2]); o[3]=(short)f2bf(a[3]);
  o[4]=(short)f2bf(b[0]); o[5]=(short)f2bf(b[1]); o[6]=(short)f2bf(b[2]); o[7]=(short)f2bf(b[3]);
  *(short8*)(dst + (size_t)i*8) = o;
}

// EmT[g][h] = softmax(ent,axis=-1)[h][g] * (log2(e)/sqrt(D)); rows g=16..31 zero-padded.
__global__ __launch_bounds__(256) void prep_em(const float* __restrict__ ent,
                                               unsigned short* __restrict__ EmT){
  int t = threadIdx.x;
  if (t < 16){
    float v[16]; float mx = -3.0e38f;
#pragma unroll
    for (int j=0;j<16;++j){ v[j] = ent[t*16 + j]; mx = fmaxf(mx, v[j]); }
    float s = 0.f;
#pragma unroll
    for (int j=0;j<16;++j){ v[j] = __expf(v[j]-mx); s += v[j]; }
    float inv = (1.f/s) * 0.125f * 1.4426950408889634f;
#pragma unroll
    for (int j=0;j<16;++j) EmT[j*16 + t] = f2bf(v[j]*inv);
  }
  EmT[256 + t] = 0; // zero pad rows 16..31 (256 entries)
}

// ---------------- mask [B][1][S][S] int32 -> bit-packed [B][S][S/32] ----------------
__global__ __launch_bounds__(256) void prep_maskbits(const int* __restrict__ mask,
                                                     unsigned* __restrict__ mb){
  int id = blockIdx.x * 256 + threadIdx.x;   // 8*1024*32 = 262144 words
  const int* src = mask + (size_t)id * 32;
  unsigned word = 0u;
#pragma unroll
  for (int c=0;c<8;++c){
    int4v v = *(const int4v*)(src + c*4);
    word |= (unsigned)(v[0]!=0) << (c*4)
          | (unsigned)(v[1]!=0) << (c*4+1)
          | (unsigned)(v[2]!=0) << (c*4+2)
          | (unsigned)(v[3]!=0) << (c*4+3);
  }
  mb[id] = word;
}

// ---------------- GEMM: C = A(bf16,[M][1024]) * W^T(bf16,[N][K] row-major) + bias ----------------
// MODE 0: out bf16 in [B][H][S][D] head layout (+ z*8388608 elem offset for Q/K/V)
// MODE 1: out f32 row-major [M][N]
template<int MODE>
__global__ __launch_bounds__(256) void gemm_bt(const unsigned short* __restrict__ A,
                                               const unsigned short* __restrict__ W4,
                                               const float* __restrict__ bias0,
                                               const float* __restrict__ bias1,
                                               const float* __restrict__ bias2,
                                               void* __restrict__ outp){
  __shared__ __align__(16) unsigned short As[4096]; // [128][32] bf16
  __shared__ __align__(16) unsigned short Bs[4096];
  const int tid = threadIdx.x;
  const int w = tid >> 6, ln = tid & 63;
  const int wm = w >> 1, wn = w & 1;
  const int lq = ln & 15, lg = ln >> 4;
  const int m0 = blockIdx.y * 128, n0 = blockIdx.x * 128;
  const int z = blockIdx.z;
  const unsigned short* Bt = W4 + (size_t)z * 1048576;
  const float* bias = (z == 0) ? bias0 : ((z == 1) ? bias1 : bias2);

  const unsigned short* Ag = A  + (size_t)(m0 + (tid >> 2)) * 1024 + (tid & 3) * 8;
  const unsigned short* Bg = Bt + (size_t)(n0 + (tid >> 2)) * 1024 + (tid & 3) * 8;
  unsigned short* lA0 = As + w * 512;
  unsigned short* lA1 = As + 2048 + w * 512;
  unsigned short* lB0 = Bs + w * 512;
  unsigned short* lB1 = Bs + 2048 + w * 512;

  f32x4 acc[4][4];
#pragma unroll
  for (int i=0;i<4;++i)
#pragma unroll
    for (int j=0;j<4;++j) acc[i][j] = zero4();

  for (int kb = 0; kb < 32; ++kb){
    const int k0 = kb * 32;
    GLL16(Ag + k0,         lA0);
    GLL16(Ag + k0 + 65536, lA1);
    GLL16(Bg + k0,         lB0);
    GLL16(Bg + k0 + 65536, lB1);
    __syncthreads();
    short8 af[4], bf_[4];
#pragma unroll
    for (int i=0;i<4;++i) af[i]  = *(const short8*)(As + (wm*64 + i*16 + lq)*32 + lg*8);
#pragma unroll
    for (int j=0;j<4;++j) bf_[j] = *(const short8*)(Bs + (wn*64 + j*16 + lq)*32 + lg*8);
#pragma unroll
    for (int i=0;i<4;++i)
#pragma unroll
      for (int j=0;j<4;++j)
        acc[i][j] = __builtin_amdgcn_mfma_f32_16x16x32_bf16(af[i], bf_[j], acc[i][j], 0, 0, 0);
    __syncthreads();
  }

  const int mrow = m0 + wm*64, ncol = n0 + wn*64;
  float bj[4];
#pragma unroll
  for (int j=0;j<4;++j) bj[j] = bias[ncol + j*16 + lq];
#pragma unroll
  for (int i=0;i<4;++i)
#pragma unroll
    for (int j=0;j<4;++j)
#pragma unroll
      for (int r=0;r<4;++r){
        float v = acc[i][j][r] + bj[j];
        int m = mrow + i*16 + lg*4 + r;
        int n = ncol + j*16 + lq;
        if (MODE == 0){
          int bb = m >> 10, sI = m & 1023, h = n >> 6, d = n & 63;
          ((unsigned short*)outp)[(size_t)z*8388608 + (((size_t)bb*16 + h)*1024 + sI)*64 + d] = f2bf(v);
        } else {
          ((float*)outp)[(size_t)m*1024 + n] = v;
        }
      }
}

// ---------------- V [bh][s][d] -> Vt [bh][d][s] ----------------
__global__ __launch_bounds__(256) void transpose_v(const unsigned short* __restrict__ V,
                                                   unsigned short* __restrict__ Vt){
  int idx = blockIdx.x * 256 + threadIdx.x;      // 128*64*128 = 1048576 total
  int s8 = idx & 127, d = (idx >> 7) & 63, bh = idx >> 13;
  const unsigned short* src = V + (size_t)bh*65536 + (size_t)s8*8*64 + d;
  short8 o;
#pragma unroll
  for (int j=0;j<8;++j) o[j] = (short)src[(size_t)j*64];
  *(short8*)(Vt + (size_t)bh*65536 + (size_t)d*1024 + (size_t)s8*8) = o;
}

// ---------------- fused attention with cross-head mix ----------------
// grid 512 blocks 1D (bid&7 = batch -> XCD-local K/V), 512 threads (8 waves), QBLK=16.
// wave w: QK^T heads 4*(w&3)..+3 on k-half (w>>2); mix q-rows {2w,2w+1};
// softmax+PV output heads {2w,2w+1} over the 16-row q-tile.
// launch_bounds (512,2): 256-VGPR cap -> natural ~116 alloc (<=128 => 2 blocks/CU), NO spills.
__global__ __launch_bounds__(512,2) void attn_fused(const unsigned short* __restrict__ Q,
    const unsigned short* __restrict__ K, const unsigned short* __restrict__ Vt,
    const unsigned* __restrict__ MB, const unsigned short* __restrict__ EmT,
    unsigned short* __restrict__ AO){
  __shared__ __align__(16) unsigned short sraw[8192]; // [q16][k32][h16] bf16, XOR-swizzled
  __shared__ __align__(16) unsigned short smix[8192]; // [g16][q16][k32] bf16, XOR-swizzled
  const int tid = threadIdx.x;
  const int w = tid >> 6, ln = tid & 63;
  const int lq = ln & 15, lg = ln >> 4;
  const int l5 = ln & 31, h5 = ln >> 5;
  const int bid = blockIdx.x;
  const int bb = bid & 7, q0 = (bid >> 3) * 16;
  const int aQ = w & 3, n0 = w >> 2, g0 = w * 2;

  const unsigned short* Qb = Q  + ((size_t)bb*16 + 4*aQ) * 65536;
  const unsigned short* Kb = K  + ((size_t)bb*16 + 4*aQ) * 65536 + (size_t)(n0*16 + lq)*64 + lg*8;
  const unsigned short* Vb = Vt + ((size_t)bb*16 + g0) * 65536;
  const unsigned* Mw = MB + (size_t)bb*32768 + (size_t)(q0 + lq)*32;

  // Em A-frag for 32x32x16: lane: EmT[l5][h5*8 + j]
  short8 emA = *(const short8*)(EmT + l5*16 + h5*8);

  // Q frags (persistent): rows q0 + lq, d = ks*32 + lg*8 + j
  short8 qf[4][2];
#pragma unroll
  for (int hh=0; hh<4; ++hh)
#pragma unroll
    for (int ks=0; ks<2; ++ks)
      qf[hh][ks] = *(const short8*)(Qb + (size_t)hh*65536 + (size_t)(q0 + lq)*64 + ks*32 + lg*8);

  f32x4 acco[2][4];
#pragma unroll
  for (int a=0;a<2;++a)
#pragma unroll
    for (int n=0;n<4;++n) acco[a][n] = zero4();
  float mst[2] = {-3.0e38f,-3.0e38f};
  float lst[2] = {0.f,0.f};

  const int kk = n0*16 + lq;

  for (int kt = 0; kt < 32; ++kt){
    const int kb = kt*32;
    // ---- QK^T: 4 heads x (16q x 16k half) ----
    f32x4 accs[4];
#pragma unroll
    for (int hh=0; hh<4; ++hh){
      short8 k0 = *(const short8*)(Kb + (size_t)hh*65536 + (size_t)kb*64);
      short8 k1 = *(const short8*)(Kb + (size_t)hh*65536 + (size_t)kb*64 + 32);
      accs[hh] = __builtin_amdgcn_mfma_f32_16x16x32_bf16(qf[hh][0], k0, zero4(), 0,0,0);
      accs[hh] = __builtin_amdgcn_mfma_f32_16x16x32_bf16(qf[hh][1], k1, accs[hh], 0,0,0);
    }
    // ---- write raw scores: sraw[q][k][h], pack 4 heads per 8B write ----
#pragma unroll
    for (int r=0;r<4;++r){
      const int qq = lg*4 + r;
      short4v pk;
      pk[0]=(short)f2bf(accs[0][r]); pk[1]=(short)f2bf(accs[1][r]);
      pk[2]=(short)f2bf(accs[2][r]); pk[3]=(short)f2bf(accs[3][r]);
      const int lin = (qq*32 + kk)*32 + aQ*8;
      const int sw  = (((kk>>2)&1)<<4) | (((qq>>2)&3)<<5);
      *(short4v*)((char*)sraw + (lin ^ sw)) = pk;
    }
    __syncthreads();
    // ---- head-mix: one 32x32x16 MFMA per q-row (M=g[16 used], N=k32, K=h16) ----
#pragma unroll
    for (int t=0;t<2;++t){
      const int qq = w*2 + t;
      const int lin = (qq*32 + l5)*32 + h5*16;
      const int sw  = (((l5>>2)&1)<<4) | (((qq>>2)&3)<<5);
      short8 sfr = *(const short8*)((const char*)sraw + (lin ^ sw));
      f32x16 md = __builtin_amdgcn_mfma_f32_32x32x16_bf16(emA, sfr, zero16(), 0,0,0);
#pragma unroll
      for (int reg=0;reg<8;++reg){
        const int gg = (reg&3) + 8*(reg>>2) + 4*h5;   // 32x32 C-layout rows < 16 kept
        int ob = gg*1024 + qq*64 + l5*2;
        ob ^= ((gg>>2)&1)<<6;
        *(short*)((char*)smix + ob) = (short)f2bf(md[reg]);
      }
    }
    __syncthreads();
    // ---- online softmax + PV (2 output heads per wave) ----
    const unsigned mw = Mw[kt];
    const unsigned mshift = mw >> (lg*8);
    const int allon = __all((int)((mshift & 0xffu) == 0xffu));
#pragma unroll
    for (int hh=0; hh<2; ++hh){
      const int gg = g0 + hh;
      const int rb = (gg*1024 + lq*64 + lg*16) ^ (((gg>>2)&1)<<6);
      short8 sm8 = *(const short8*)((const char*)smix + rb);
      short8 vfr[4];
#pragma unroll
      for (int n=0;n<4;++n)
        vfr[n] = *(const short8*)(Vb + (size_t)hh*65536 + (size_t)(n*16 + lq)*1024 + kb + lg*8);
      float s[8];
#pragma unroll
      for (int j=0;j<8;++j) s[j] = bf2f((unsigned short)sm8[j]);
      if (!allon){
#pragma unroll
        for (int j=0;j<8;++j) if (!((mshift>>j)&1u)) s[j] = -1.44269504e9f; // -1e9 * log2e
      }
      float pm = s[0];
#pragma unroll
      for (int j=1;j<8;++j) pm = fmaxf(pm, s[j]);
      pm = fmaxf(pm, __shfl_xor(pm, 16, 64));
      pm = fmaxf(pm, __shfl_xor(pm, 32, 64));
      const float mo = mst[hh];
      const float mn = fmaxf(mo, pm);
      const float sc = exp2f(mo - mn);
      float p[8]; float ps = 0.f;
#pragma unroll
      for (int j=0;j<8;++j){ p[j] = exp2f(s[j] - mn); ps += p[j]; }
      ps += __shfl_xor(ps, 16, 64);
      ps += __shfl_xor(ps, 32, 64);
      lst[hh] = lst[hh]*sc + ps;
      mst[hh] = mn;
      short8 pa;
#pragma unroll
      for (int j=0;j<8;++j) pa[j] = (short)f2bf(p[j]);
      const float scr0 = __shfl(sc, lg*4 + 0, 64);
      const float scr1 = __shfl(sc, lg*4 + 1, 64);
      const float scr2 = __shfl(sc, lg*4 + 2, 64);
      const float scr3 = __shfl(sc, lg*4 + 3, 64);
#pragma unroll
      for (int n=0;n<4;++n){
        acco[hh][n][0] *= scr0; acco[hh][n][1] *= scr1;
        acco[hh][n][2] *= scr2; acco[hh][n][3] *= scr3;
      }
#pragma unroll
      for (int n=0;n<4;++n)
        acco[hh][n] = __builtin_amdgcn_mfma_f32_16x16x32_bf16(pa, vfr[n], acco[hh][n], 0,0,0);
    }
  }
  // ---- normalize + write AO [B*S][E] bf16 ----
#pragma unroll
  for (int hh=0; hh<2; ++hh){
    const int gg = g0 + hh;
    const float linv = 1.0f / lst[hh];
    const float l0 = __shfl(linv, lg*4+0, 64), l1 = __shfl(linv, lg*4+1, 64);
    const float l2 = __shfl(linv, lg*4+2, 64), l3 = __shfl(linv, lg*4+3, 64);
#pragma unroll
    for (int n=0;n<4;++n){
      const int e = gg*64 + n*16 + lq;
      const size_t base = ((size_t)bb*1024 + (size_t)(q0 + lg*4))*1024 + e;
      AO[base         ] = f2bf(acco[hh][n][0]*l0);
      AO[base + 1024  ] = f2bf(acco[hh][n][1]*l1);
      AO[base + 2048  ] = f2bf(acco[hh][n][2]*l2);
      AO[base + 3072  ] = f2bf(acco[hh][n][3]*l3);
    }
  }
}

// ---------------- host launcher ----------------
extern "C" void kernel_launch(void* const* d_in, const int* in_sizes, int n_in,
                              void* d_out, int out_size, void* d_ws, size_t ws_size,
                              hipStream_t stream){
  const float* x   = (const float*)d_in[0];
  const int*   msk = (const int*)  d_in[1];
  const float* Wq  = (const float*)d_in[2];
  const float* bq  = (const float*)d_in[3];
  const float* Wk  = (const float*)d_in[4];
  const float* bk  = (const float*)d_in[5];
  const float* Wv  = (const float*)d_in[6];
  const float* bv  = (const float*)d_in[7];
  const float* Wo  = (const float*)d_in[8];
  const float* bo  = (const float*)d_in[9];
  const float* ent = (const float*)d_in[10];

  char* ws = (char*)d_ws;
  unsigned short* xb  = (unsigned short*)(ws);                 // 16 MiB  (later reused as Vt)
  unsigned short* Wb  = (unsigned short*)(ws + 16777216);      // 4 x 2 MiB bf16 weights
  unsigned short* qkv = (unsigned short*)(ws + 25165824);      // Q,K,V: 3 x 16 MiB
  unsigned short* EmT = (unsigned short*)(ws + 75497472);      // 1 KiB
  unsigned*       MB  = (unsigned*)     (ws + 75499520);       // 1 MiB bit-packed mask
  unsigned short* Vt  = xb;                                    // reuse (xb dead after GEMMs)
  unsigned short* AO  = qkv + (size_t)2*8388608;               // reuse V slot (dead after transpose)

  cast_f32_bf16<<<4096, 256, 0, stream>>>(x,  xb,            1048576);
  cast_f32_bf16<<<512,  256, 0, stream>>>(Wq, Wb,            131072);
  cast_f32_bf16<<<512,  256, 0, stream>>>(Wk, Wb + 1048576,  131072);
  cast_f32_bf16<<<512,  256, 0, stream>>>(Wv, Wb + 2097152,  131072);
  cast_f32_bf16<<<512,  256, 0, stream>>>(Wo, Wb + 3145728,  131072);
  prep_em<<<1, 256, 0, stream>>>(ent, EmT);
  prep_maskbits<<<1024, 256, 0, stream>>>(msk, MB);

  gemm_bt<0><<<dim3(8,64,3), 256, 0, stream>>>(xb, Wb, bq, bk, bv, (void*)qkv);
  transpose_v<<<4096, 256, 0, stream>>>(qkv + (size_t)2*8388608, Vt);
  attn_fused<<<512, 512, 0, stream>>>(qkv, qkv + 8388608, Vt, MB, EmT, AO);
  gemm_bt<1><<<dim3(8,64,1), 256, 0, stream>>>(AO, Wb + 3145728, bo, bo, bo, d_out);

  (void)in_sizes; (void)n_in; (void)out_size; (void)ws_size;
}

// Round 7
// 432.903 us; speedup vs baseline: 1.1476x; 1.0283x over previous
//
#include <hip/hip_runtime.h>

#define DEVINL static __device__ __forceinline__

typedef __attribute__((ext_vector_type(4)))  float f32x4;
typedef __attribute__((ext_vector_type(16))) float f32x16;
typedef __attribute__((ext_vector_type(4)))  float float4_t;
typedef __attribute__((ext_vector_type(8)))  short short8;
typedef __attribute__((ext_vector_type(4)))  short short4v;
typedef __attribute__((ext_vector_type(4)))  int   int4v;
typedef __attribute__((ext_vector_type(2)))  unsigned u32x2;

DEVINL unsigned short f2bf(float f){
  union { float f; unsigned int u; } x; x.f = f;
  return (unsigned short)((x.u + 0x7fffu + ((x.u >> 16) & 1u)) >> 16);
}
DEVINL float bf2f(unsigned short h){
  union { unsigned int u; float f; } x; x.u = ((unsigned int)h) << 16;
  return x.f;
}
DEVINL f32x4 zero4(){ f32x4 z; z[0]=0.f; z[1]=0.f; z[2]=0.f; z[3]=0.f; return z; }
DEVINL f32x16 zero16(){ f32x16 z;
#pragma unroll
  for (int e=0;e<16;++e) z[e]=0.f;
  return z; }

// async global->LDS, 16B per lane
#define GLL16(gp, lp) __builtin_amdgcn_global_load_lds( \
    (const __attribute__((address_space(1))) void*)(gp), \
    (__attribute__((address_space(3))) void*)(lp), 16, 0, 0)

// ---------------- prep: f32 -> bf16 casts ----------------
__global__ __launch_bounds__(256) void cast_f32_bf16(const float* __restrict__ src,
                                                     unsigned short* __restrict__ dst, int n8){
  int i = blockIdx.x * 256 + threadIdx.x;
  if (i >= n8) return;
  const float4_t* s = (const float4_t*)src;
  float4_t a = s[2*i], b = s[2*i+1];
  short8 o;
  o[0]=(short)f2bf(a[0]); o[1]=(short)f2bf(a[1]); o[2]=(short)f2bf(a[2]); o[3]=(short)f2bf(a[3]);
  o[4]=(short)f2bf(b[0]); o[5]=(short)f2bf(b[1]); o[6]=(short)f2bf(b[2]); o[7]=(short)f2bf(b[3]);
  *(short8*)(dst + (size_t)i*8) = o;
}

// EmT[g][h] = softmax(ent,axis=-1)[h][g] * (log2(e)/sqrt(D)); rows g=16..31 zero-padded.
__global__ __launch_bounds__(256) void prep_em(const float* __restrict__ ent,
                                               unsigned short* __restrict__ EmT){
  int t = threadIdx.x;
  if (t < 16){
    float v[16]; float mx = -3.0e38f;
#pragma unroll
    for (int j=0;j<16;++j){ v[j] = ent[t*16 + j]; mx = fmaxf(mx, v[j]); }
    float s = 0.f;
#pragma unroll
    for (int j=0;j<16;++j){ v[j] = __expf(v[j]-mx); s += v[j]; }
    float inv = (1.f/s) * 0.125f * 1.4426950408889634f;
#pragma unroll
    for (int j=0;j<16;++j) EmT[j*16 + t] = f2bf(v[j]*inv);
  }
  EmT[256 + t] = 0; // zero pad rows 16..31
}

// ---------------- mask [B][1][S][S] int32 -> bit-packed [B][S][S/32] ----------------
__global__ __launch_bounds__(256) void prep_maskbits(const int* __restrict__ mask,
                                                     unsigned* __restrict__ mb){
  int id = blockIdx.x * 256 + threadIdx.x;   // 262144 words
  const int* src = mask + (size_t)id * 32;
  unsigned word = 0u;
#pragma unroll
  for (int c=0;c<8;++c){
    int4v v = *(const int4v*)(src + c*4);
    word |= (unsigned)(v[0]!=0) << (c*4)
          | (unsigned)(v[1]!=0) << (c*4+1)
          | (unsigned)(v[2]!=0) << (c*4+2)
          | (unsigned)(v[3]!=0) << (c*4+3);
  }
  mb[id] = word;
}

// ---------------- GEMM: C = A(bf16,[M][1024]) * W^T(bf16,[N][K]) + bias ----------------
template<int MODE>
__global__ __launch_bounds__(256) void gemm_bt(const unsigned short* __restrict__ A,
                                               const unsigned short* __restrict__ W4,
                                               const float* __restrict__ bias0,
                                               const float* __restrict__ bias1,
                                               const float* __restrict__ bias2,
                                               void* __restrict__ outp){
  __shared__ __align__(16) unsigned short As[4096];
  __shared__ __align__(16) unsigned short Bs[4096];
  const int tid = threadIdx.x;
  const int w = tid >> 6, ln = tid & 63;
  const int wm = w >> 1, wn = w & 1;
  const int lq = ln & 15, lg = ln >> 4;
  const int m0 = blockIdx.y * 128, n0 = blockIdx.x * 128;
  const int z = blockIdx.z;
  const unsigned short* Bt = W4 + (size_t)z * 1048576;
  const float* bias = (z == 0) ? bias0 : ((z == 1) ? bias1 : bias2);

  const unsigned short* Ag = A  + (size_t)(m0 + (tid >> 2)) * 1024 + (tid & 3) * 8;
  const unsigned short* Bg = Bt + (size_t)(n0 + (tid >> 2)) * 1024 + (tid & 3) * 8;
  unsigned short* lA0 = As + w * 512;
  unsigned short* lA1 = As + 2048 + w * 512;
  unsigned short* lB0 = Bs + w * 512;
  unsigned short* lB1 = Bs + 2048 + w * 512;

  f32x4 acc[4][4];
#pragma unroll
  for (int i=0;i<4;++i)
#pragma unroll
    for (int j=0;j<4;++j) acc[i][j] = zero4();

  for (int kb = 0; kb < 32; ++kb){
    const int k0 = kb * 32;
    GLL16(Ag + k0,         lA0);
    GLL16(Ag + k0 + 65536, lA1);
    GLL16(Bg + k0,         lB0);
    GLL16(Bg + k0 + 65536, lB1);
    __syncthreads();
    short8 af[4], bf_[4];
#pragma unroll
    for (int i=0;i<4;++i) af[i]  = *(const short8*)(As + (wm*64 + i*16 + lq)*32 + lg*8);
#pragma unroll
    for (int j=0;j<4;++j) bf_[j] = *(const short8*)(Bs + (wn*64 + j*16 + lq)*32 + lg*8);
#pragma unroll
    for (int i=0;i<4;++i)
#pragma unroll
      for (int j=0;j<4;++j)
        acc[i][j] = __builtin_amdgcn_mfma_f32_16x16x32_bf16(af[i], bf_[j], acc[i][j], 0, 0, 0);
    __syncthreads();
  }

  const int mrow = m0 + wm*64, ncol = n0 + wn*64;
  float bj[4];
#pragma unroll
  for (int j=0;j<4;++j) bj[j] = bias[ncol + j*16 + lq];
#pragma unroll
  for (int i=0;i<4;++i)
#pragma unroll
    for (int j=0;j<4;++j)
#pragma unroll
      for (int r=0;r<4;++r){
        float v = acc[i][j][r] + bj[j];
        int m = mrow + i*16 + lg*4 + r;
        int n = ncol + j*16 + lq;
        if (MODE == 0){
          int bb = m >> 10, sI = m & 1023, h = n >> 6, d = n & 63;
          ((unsigned short*)outp)[(size_t)z*8388608 + (((size_t)bb*16 + h)*1024 + sI)*64 + d] = f2bf(v);
        } else {
          ((float*)outp)[(size_t)m*1024 + n] = v;
        }
      }
}

// ---------------- V [bh][s][d] -> Vt [bh][d][s] ----------------
__global__ __launch_bounds__(256) void transpose_v(const unsigned short* __restrict__ V,
                                                   unsigned short* __restrict__ Vt){
  int idx = blockIdx.x * 256 + threadIdx.x;
  int s8 = idx & 127, d = (idx >> 7) & 63, bh = idx >> 13;
  const unsigned short* src = V + (size_t)bh*65536 + (size_t)s8*8*64 + d;
  short8 o;
#pragma unroll
  for (int j=0;j<8;++j) o[j] = (short)src[(size_t)j*64];
  *(short8*)(Vt + (size_t)bh*65536 + (size_t)d*1024 + (size_t)s8*8) = o;
}

// ---------------- fused attention with cross-head mix (v6 = v5 algorithm, safe sync/convert) ----------------
// 512 blocks (bid&7=batch, XCD-local K/V), 8 waves, QBLK=16, KVBLK=64, 16 iters.
// PV operand-swapped: acco C-layout col = q = lane&15 -> softmax state and
// accumulator share lane indexing (no rescale shuffles).
__global__ __launch_bounds__(512,2) void attn_fused(const unsigned short* __restrict__ Q,
    const unsigned short* __restrict__ K, const unsigned short* __restrict__ Vt,
    const unsigned* __restrict__ MB, const unsigned short* __restrict__ EmT,
    unsigned short* __restrict__ AO){
  __shared__ __align__(16) unsigned short sraw[16384]; // [q16][k64][h16] swizzled
  __shared__ __align__(16) unsigned short smix[16384]; // [g16][q16][k64] swizzled
  const int tid = threadIdx.x;
  const int w = tid >> 6, ln = tid & 63;
  const int lq = ln & 15, lg = ln >> 4;
  const int l5 = ln & 31, h5 = ln >> 5;
  const int bid = blockIdx.x;
  const int bb = bid & 7, q0 = (bid >> 3) * 16;
  const int aQ = w & 3, n0 = w >> 2, g0 = w * 2;

  const unsigned short* Qb = Q  + ((size_t)bb*16 + 4*aQ) * 65536;
  const unsigned short* Kb = K  + ((size_t)bb*16 + 4*aQ) * 65536 + (size_t)(n0*32 + lq)*64 + lg*8;
  const unsigned short* Vb = Vt + ((size_t)bb*16 + g0) * 65536;
  const unsigned* Mwp = MB + (size_t)bb*32768 + (size_t)(q0 + lq)*32;

  short8 emA = *(const short8*)(EmT + l5*16 + h5*8);

  short8 qf[4][2];
#pragma unroll
  for (int hh=0; hh<4; ++hh)
#pragma unroll
    for (int ks=0; ks<2; ++ks)
      qf[hh][ks] = *(const short8*)(Qb + (size_t)hh*65536 + (size_t)(q0 + lq)*64 + ks*32 + lg*8);

  f32x4 acco[2][4];
#pragma unroll
  for (int a=0;a<2;++a)
#pragma unroll
    for (int n=0;n<4;++n) acco[a][n] = zero4();
  float mst[2] = {-3.0e38f,-3.0e38f};
  float lst[2] = {0.f,0.f};

  for (int kt = 0; kt < 16; ++kt){
    const int kb = kt*64;
    // ---- prefetch mask + V for this tile (consumed after 2 barriers) ----
    const u32x2 mw = *(const u32x2*)(Mwp + kt*2);
    short8 vfr[2][4][2];
#pragma unroll
    for (int hh=0;hh<2;++hh)
#pragma unroll
      for (int n=0;n<4;++n)
#pragma unroll
        for (int kh=0;kh<2;++kh)
          vfr[hh][n][kh] = *(const short8*)(Vb + (size_t)hh*65536 + (size_t)(n*16 + lq)*1024 + kb + kh*32 + lg*8);

    // ---- QK^T: 4 heads x (16q x 32k half) ----
    f32x4 accs[4][2];
#pragma unroll
    for (int hh=0; hh<4; ++hh){
      short8 kf[2][2];
#pragma unroll
      for (int n=0;n<2;++n)
#pragma unroll
        for (int ks=0;ks<2;++ks)
          kf[n][ks] = *(const short8*)(Kb + (size_t)hh*65536 + (size_t)(kb + n*16)*64 + ks*32);
#pragma unroll
      for (int n=0;n<2;++n){
        accs[hh][n] = __builtin_amdgcn_mfma_f32_16x16x32_bf16(qf[hh][0], kf[n][0], zero4(), 0,0,0);
        accs[hh][n] = __builtin_amdgcn_mfma_f32_16x16x32_bf16(qf[hh][1], kf[n][1], accs[hh][n], 0,0,0);
      }
    }
    // ---- pack + store raw scores: sraw[q][k][h] ----
#pragma unroll
    for (int n=0;n<2;++n)
#pragma unroll
      for (int r=0;r<4;++r){
        const int qq = lg*4 + r;
        const int kk = n0*32 + n*16 + lq;
        short4v pk;
        pk[0]=(short)f2bf(accs[0][n][r]); pk[1]=(short)f2bf(accs[1][n][r]);
        pk[2]=(short)f2bf(accs[2][n][r]); pk[3]=(short)f2bf(accs[3][n][r]);
        const int lin = (qq*64 + kk)*32 + aQ*8;
        const int sw  = (((kk>>2)&1)<<4) | (((qq>>2)&3)<<5);
        *(short4v*)((char*)sraw + (lin ^ sw)) = pk;
      }
    __syncthreads();
    // ---- head-mix: 32x32x16 MFMA per (q-row, k-half) ----
#pragma unroll
    for (int t=0;t<4;++t){
      const int qq = w*2 + (t&1);
      const int kh = t>>1;
      const int kk = kh*32 + l5;
      const int lin = (qq*64 + kk)*32 + h5*16;
      const int sw  = (((kk>>2)&1)<<4) | (((qq>>2)&3)<<5);
      short8 sfr = *(const short8*)((const char*)sraw + (lin ^ sw));
      f32x16 md = __builtin_amdgcn_mfma_f32_32x32x16_bf16(emA, sfr, zero16(), 0,0,0);
#pragma unroll
      for (int reg=0;reg<8;++reg){
        const int gg = (reg&3) + 8*(reg>>2) + 4*h5;   // rows < 16 kept
        int ob = gg*2048 + qq*128 + kk*2;
        ob ^= ((qq&7)<<4) ^ (((gg>>2)&1)<<6);
        *(short*)((char*)smix + ob) = (short)f2bf(md[reg]);
      }
    }
    __syncthreads();
    // ---- online softmax + PV (state & acco indexed by q = lane&15) ----
    const unsigned mb0 = (mw[0] >> (lg*8)) & 0xffu;
    const unsigned mb1 = (mw[1] >> (lg*8)) & 0xffu;
    const int allon = __all((int)((mb0 & mb1) == 0xffu));
#pragma unroll
    for (int hh=0; hh<2; ++hh){
      const int gg = g0 + hh;
      const int swc = ((lq&7)<<4) ^ (((gg>>2)&1)<<6);
      const int base = gg*2048 + lq*128 + lg*16;
      short8 sm0 = *(const short8*)((const char*)smix + ((base      ) ^ swc));
      short8 sm1 = *(const short8*)((const char*)smix + ((base + 64 ) ^ swc));
      float s[16];
#pragma unroll
      for (int j=0;j<8;++j){ s[j] = bf2f((unsigned short)sm0[j]); s[8+j] = bf2f((unsigned short)sm1[j]); }
      if (!allon){
#pragma unroll
        for (int j=0;j<8;++j){
          if (!((mb0>>j)&1u)) s[j]    = -1.44269504e9f;
          if (!((mb1>>j)&1u)) s[8+j]  = -1.44269504e9f;
        }
      }
      float m01 = fmaxf(s[0],s[1]),  m23 = fmaxf(s[2],s[3]);
      float m45 = fmaxf(s[4],s[5]),  m67 = fmaxf(s[6],s[7]);
      float m89 = fmaxf(s[8],s[9]),  mab = fmaxf(s[10],s[11]);
      float mcd = fmaxf(s[12],s[13]),mef = fmaxf(s[14],s[15]);
      float pm = fmaxf(fmaxf(fmaxf(m01,m23), fmaxf(m45,m67)),
                       fmaxf(fmaxf(m89,mab), fmaxf(mcd,mef)));
      pm = fmaxf(pm, __shfl_xor(pm, 16, 64));
      pm = fmaxf(pm, __shfl_xor(pm, 32, 64));
      const float mo = mst[hh];
      const float mn = fmaxf(mo, pm);
      const float sc = exp2f(mo - mn);
      float p[16];
#pragma unroll
      for (int j=0;j<16;++j) p[j] = exp2f(s[j] - mn);
      float ps = 0.f;
#pragma unroll
      for (int j=0;j<16;++j) ps += p[j];
      ps += __shfl_xor(ps, 16, 64);
      ps += __shfl_xor(ps, 32, 64);
      lst[hh] = lst[hh]*sc + ps;
      mst[hh] = mn;
      short8 pa0, pa1;
#pragma unroll
      for (int j=0;j<8;++j){ pa0[j] = (short)f2bf(p[j]); pa1[j] = (short)f2bf(p[8+j]); }
#pragma unroll
      for (int n=0;n<4;++n){
        acco[hh][n][0] *= sc; acco[hh][n][1] *= sc;
        acco[hh][n][2] *= sc; acco[hh][n][3] *= sc;
      }
#pragma unroll
      for (int n=0;n<4;++n){
        acco[hh][n] = __builtin_amdgcn_mfma_f32_16x16x32_bf16(vfr[hh][n][0], pa0, acco[hh][n], 0,0,0);
        acco[hh][n] = __builtin_amdgcn_mfma_f32_16x16x32_bf16(vfr[hh][n][1], pa1, acco[hh][n], 0,0,0);
      }
    }
  }
  // ---- normalize + write AO [B*S][E] bf16 (acco rows = d, cols = q) ----
#pragma unroll
  for (int hh=0; hh<2; ++hh){
    const int gg = g0 + hh;
    const float linv = 1.0f / lst[hh];
    const size_t rowb = ((size_t)(bb*1024 + q0 + lq))*2048;
#pragma unroll
    for (int n=0;n<4;++n){
      unsigned w0 = (unsigned)f2bf(acco[hh][n][0]*linv) | ((unsigned)f2bf(acco[hh][n][1]*linv) << 16);
      unsigned w1 = (unsigned)f2bf(acco[hh][n][2]*linv) | ((unsigned)f2bf(acco[hh][n][3]*linv) << 16);
      const int e = gg*64 + n*16 + lg*4;
      *(unsigned*)((char*)AO + rowb + (size_t)e*2    ) = w0;
      *(unsigned*)((char*)AO + rowb + (size_t)e*2 + 4) = w1;
    }
  }
}

// ---------------- host launcher ----------------
extern "C" void kernel_launch(void* const* d_in, const int* in_sizes, int n_in,
                              void* d_out, int out_size, void* d_ws, size_t ws_size,
                              hipStream_t stream){
  const float* x   = (const float*)d_in[0];
  const int*   msk = (const int*)  d_in[1];
  const float* Wq  = (const float*)d_in[2];
  const float* bq  = (const float*)d_in[3];
  const float* Wk  = (const float*)d_in[4];
  const float* bk  = (const float*)d_in[5];
  const float* Wv  = (const float*)d_in[6];
  const float* bv  = (const float*)d_in[7];
  const float* Wo  = (const float*)d_in[8];
  const float* bo  = (const float*)d_in[9];
  const float* ent = (const float*)d_in[10];

  char* ws = (char*)d_ws;
  unsigned short* xb  = (unsigned short*)(ws);                 // 16 MiB (reused as Vt)
  unsigned short* Wb  = (unsigned short*)(ws + 16777216);      // 4 x 2 MiB bf16 weights
  unsigned short* qkv = (unsigned short*)(ws + 25165824);      // Q,K,V: 3 x 16 MiB
  unsigned short* EmT = (unsigned short*)(ws + 75497472);      // 1 KiB
  unsigned*       MB  = (unsigned*)     (ws + 75499520);       // 1 MiB bit-packed mask
  unsigned short* Vt  = xb;
  unsigned short* AO  = qkv + (size_t)2*8388608;

  cast_f32_bf16<<<4096, 256, 0, stream>>>(x,  xb,            1048576);
  cast_f32_bf16<<<512,  256, 0, stream>>>(Wq, Wb,            131072);
  cast_f32_bf16<<<512,  256, 0, stream>>>(Wk, Wb + 1048576,  131072);
  cast_f32_bf16<<<512,  256, 0, stream>>>(Wv, Wb + 2097152,  131072);
  cast_f32_bf16<<<512,  256, 0, stream>>>(Wo, Wb + 3145728,  131072);
  prep_em<<<1, 256, 0, stream>>>(ent, EmT);
  prep_maskbits<<<1024, 256, 0, stream>>>(msk, MB);

  gemm_bt<0><<<dim3(8,64,3), 256, 0, stream>>>(xb, Wb, bq, bk, bv, (void*)qkv);
  transpose_v<<<4096, 256, 0, stream>>>(qkv + (size_t)2*8388608, Vt);
  attn_fused<<<512, 512, 0, stream>>>(qkv, qkv + 8388608, Vt, MB, EmT, AO);
  gemm_bt<1><<<dim3(8,64,1), 256, 0, stream>>>(AO, Wb + 3145728, bo, bo, bo, d_out);

  (void)in_sizes; (void)n_in; (void)out_size; (void)ws_size;
}